// Round 4
// baseline (267.902 us; speedup 1.0000x reference)
//
#include <hip/hip_runtime.h>

typedef unsigned short u16;
typedef short s16x8 __attribute__((ext_vector_type(8)));
typedef float f32x4 __attribute__((ext_vector_type(4)));
typedef u16 u16x8 __attribute__((ext_vector_type(8)));

#define HW_N 16384   // 128*128 pixels
#define NCH  2048
// A_bf layout: [kc 0..32][pixel 16384][64 k]  (slab 32 = dense features + pad)
// W_bf layout: [kc 0..32][ch 2048][64 k]
// Wd   layout: [kc 0..31][j 48][64 k]

__device__ __forceinline__ u16 f2bf(float f) {
  union { float f; unsigned u; } v; v.f = f;
  unsigned r = v.u + 0x7FFFu + ((v.u >> 16) & 1u);  // RNE
  return (u16)(r >> 16);
}
__device__ __forceinline__ float bf2f(u16 u) {
  union { unsigned u; float f; } v; v.u = ((unsigned)u) << 16; return v.f;
}
__device__ __forceinline__ float lrelu(float v) { return v >= 0.0f ? v : 0.2f * v; }

__device__ __forceinline__ void gload_lds16(const u16* g, u16* l) {
  __builtin_amdgcn_global_load_lds((const __attribute__((address_space(1))) void*)g,
                                   (__attribute__((address_space(3))) void*)l, 16, 0, 0);
}

// ---------------- kernel 1: LN stats + pooled partial + coalesced bf16 A copy ----------------
__global__ __launch_bounds__(256) void k_stats(const float* __restrict__ trans,
                                               u16* __restrict__ A_bf,
                                               float* __restrict__ pooled_sum) {
  const int z = blockIdx.x;
  const int tid = threadIdx.x;
  const int ptile = blockIdx.y;
  const int p = ptile * 256 + tid;
  const float* src = trans + (size_t)z * 64 * HW_N + p;
  float x[64];
#pragma unroll
  for (int c = 0; c < 64; ++c) x[c] = src[(size_t)c * HW_N];
  float sum = 0.f, sq = 0.f;
#pragma unroll
  for (int c = 0; c < 64; ++c) { sum += x[c]; sq += x[c] * x[c]; }
  const float mu = sum * (1.0f / 64.0f);
  const float var = sq * (1.0f / 64.0f) - mu * mu;
  const float rstd = rsqrtf(var + 1e-5f);

  __shared__ __align__(16) u16 rawt[256 * 64];
  __shared__ __align__(16) u16 normt[256 * 64];
  const int r7 = tid & 7;
#pragma unroll
  for (int c8 = 0; c8 < 8; ++c8) {
    u16x8 wr, wn;
#pragma unroll
    for (int e = 0; e < 8; ++e) {
      float xv = x[c8 * 8 + e];
      wr[e] = f2bf(xv);
      wn[e] = f2bf((xv - mu) * rstd);
    }
    const int off = tid * 64 + ((c8 ^ r7) << 3);
    *(u16x8*)&rawt[off] = wr;
    *(u16x8*)&normt[off] = wn;
  }
  __syncthreads();

  u16* gbase = A_bf + ((size_t)z * HW_N + (size_t)ptile * 256) * 64;
#pragma unroll
  for (int i = 0; i < 8; ++i) {
    const int o = i * 256 + tid;
    const int row = o >> 3, kc = o & 7;
    u16x8 v = *(const u16x8*)&rawt[row * 64 + ((kc ^ (row & 7)) << 3)];
    *(u16x8*)(gbase + o * 8) = v;
  }

  const int c = tid & 63, q = tid >> 6;
  const int kc2 = c >> 3, e2 = c & 7;
  float s = 0.f;
#pragma unroll 8
  for (int i = 0; i < 64; ++i) {
    const int row = q * 64 + i;
    s += bf2f(normt[row * 64 + ((kc2 ^ (row & 7)) << 3) + e2]);
  }
  __shared__ float red2[4][64];
  red2[q][c] = s;
  __syncthreads();
  if (tid < 64) {
    atomicAdd(&pooled_sum[z * 64 + tid],
              red2[0][tid] + red2[1][tid] + red2[2][tid] + red2[3][tid]);
  }
}

// ---------------- kernel 2a: pack dense weights (first 2048 rows) -> Wd bf16 ----------------
__global__ __launch_bounds__(256) void k_wdense(const float* __restrict__ dw0,
                                                const float* __restrict__ dw1,
                                                const float* __restrict__ dw2,
                                                u16* __restrict__ Wd) {
  const int kc = blockIdx.x;  // 0..31
  __shared__ float tile[64][49];
  for (int idx = threadIdx.x; idx < 3072; idx += 256) {
    const int kk = idx / 48, j = idx % 48;
    const int k = kc * 64 + kk;
    float v = (j < 16) ? dw0[k * 16 + j]
            : (j < 32) ? dw1[k * 16 + (j - 16)]
                       : dw2[k * 16 + (j - 32)];
    tile[kk][j] = v;
  }
  __syncthreads();
  for (int idx = threadIdx.x; idx < 3072; idx += 256) {
    const int j = idx / 64, kk = idx % 64;
    Wd[((size_t)kc * 48 + j) * 64 + kk] = f2bf(tile[kk][j]);
  }
}

// ---------------- kernel 2b: G[pix][48] = A_bf[:,0:2048] @ Wd  (MFMA, K-split 2) ----------------
__global__ __launch_bounds__(256) void k_dgemm(const u16* __restrict__ A_bf,
                                               const u16* __restrict__ Wd,
                                               float* __restrict__ G_part) {
  __shared__ __align__(16) u16 lsA[128 * 64];  // 16 KB
  __shared__ __align__(16) u16 lsW[48 * 64];   // 6 KB
  const int tid = threadIdx.x;
  const int lane = tid & 63;
  const int wave = __builtin_amdgcn_readfirstlane(tid >> 6);
  const int mb = blockIdx.x;
  const int ks = blockIdx.y;
  const int srow = lane >> 3;
  const int skg = (lane & 7) ^ srow;
  f32x4 acc[3][2] = {};

  for (int t = 0; t < 16; ++t) {
    const int kc = ks * 16 + t;
    const u16* slabA = A_bf + ((size_t)kc * HW_N + (size_t)mb * 128) * 64;
    const u16* slabW = Wd + (size_t)kc * 48 * 64;
#pragma unroll
    for (int i = 0; i < 4; ++i) {
      const int c = wave * 4 + i;
      gload_lds16(slabA + (c * 8 + srow) * 64 + skg * 8, &lsA[c * 512]);
    }
    if (wave < 3) {
#pragma unroll
      for (int i = 0; i < 2; ++i) {
        const int c = wave * 2 + i;
        gload_lds16(slabW + (c * 8 + srow) * 64 + skg * 8, &lsW[c * 512]);
      }
    }
    asm volatile("s_waitcnt vmcnt(0)" ::: "memory");
    __syncthreads();

    const int r16 = lane & 15, kgrp = lane >> 4, x7 = lane & 7;
#pragma unroll
    for (int s = 0; s < 2; ++s) {
      s16x8 wf[3], af[2];
#pragma unroll
      for (int f = 0; f < 3; ++f) {
        const int rowW = f * 16 + r16;
        wf[f] = *(const s16x8*)((const char*)lsW + rowW * 128 + (((s * 4 + kgrp) ^ x7) << 4));
      }
#pragma unroll
      for (int g = 0; g < 2; ++g) {
        const int rowA = wave * 32 + g * 16 + r16;
        af[g] = *(const s16x8*)((const char*)lsA + rowA * 128 + (((s * 4 + kgrp) ^ x7) << 4));
      }
#pragma unroll
      for (int f = 0; f < 3; ++f)
#pragma unroll
        for (int g = 0; g < 2; ++g)
          acc[f][g] = __builtin_amdgcn_mfma_f32_16x16x32_bf16(wf[f], af[g], acc[f][g], 0, 0, 0);
    }
    __syncthreads();
  }

  const int r16 = lane & 15, rg = lane >> 4;
  float* gp = G_part + (size_t)ks * 48 * HW_N;
#pragma unroll
  for (int f = 0; f < 3; ++f)
#pragma unroll
    for (int r = 0; r < 4; ++r) {
      const int j = f * 16 + rg * 4 + r;
#pragma unroll
      for (int g = 0; g < 2; ++g) {
        const int pix = mb * 128 + wave * 32 + g * 16 + r16;
        gp[(size_t)j * HW_N + pix] = acc[f][g][r];
      }
    }
}

// ---------------- kernel 2c: finalize dense chain -> A_bf slab 32 ----------------
__global__ __launch_bounds__(256) void k_dfin(const float* __restrict__ G_part,
    const float* __restrict__ dw1, const float* __restrict__ dw2,
    const float* __restrict__ db0, const float* __restrict__ db1,
    const float* __restrict__ db2, u16* __restrict__ A_bf) {
  const int tid = threadIdx.x;
  const int pix = blockIdx.x * 256 + tid;
  __shared__ float w1t[16][16];
  __shared__ float w2t[32][16];
  __shared__ float biases[48];
  if (tid < 256) w1t[tid >> 4][tid & 15] = dw1[(2048 + (tid >> 4)) * 16 + (tid & 15)];
  for (int idx = tid; idx < 512; idx += 256)
    w2t[idx >> 4][idx & 15] = dw2[(2048 + (idx >> 4)) * 16 + (idx & 15)];
  if (tid < 48) biases[tid] = (tid < 16) ? db0[tid] : (tid < 32) ? db1[tid - 16] : db2[tid - 32];
  __syncthreads();

  float g[48];
#pragma unroll
  for (int j = 0; j < 48; ++j)
    g[j] = G_part[(size_t)j * HW_N + pix] + G_part[(size_t)(48 + j) * HW_N + pix];

  float f0[16], f1[16], f2[16];
#pragma unroll
  for (int j = 0; j < 16; ++j) f0[j] = lrelu(g[j] + biases[j]);
#pragma unroll
  for (int j = 0; j < 16; ++j) {
    float a = g[16 + j] + biases[16 + j];
#pragma unroll
    for (int i = 0; i < 16; ++i) a += f0[i] * w1t[i][j];
    f1[j] = lrelu(a);
  }
#pragma unroll
  for (int j = 0; j < 16; ++j) {
    float a = g[32 + j] + biases[32 + j];
#pragma unroll
    for (int i = 0; i < 16; ++i) a += f0[i] * w2t[i][j];
#pragma unroll
    for (int i = 0; i < 16; ++i) a += f1[i] * w2t[16 + i][j];
    f2[j] = lrelu(a);
  }
  u16* dst = A_bf + ((size_t)32 * HW_N + pix) * 64;
  u16x8 w;
#pragma unroll
  for (int b = 0; b < 2; ++b) {
#pragma unroll
    for (int e = 0; e < 8; ++e) w[e] = f2bf(f0[b * 8 + e]);
    *(u16x8*)(dst + b * 8) = w;
  }
#pragma unroll
  for (int b = 0; b < 2; ++b) {
#pragma unroll
    for (int e = 0; e < 8; ++e) w[e] = f2bf(f1[b * 8 + e]);
    *(u16x8*)(dst + 16 + b * 8) = w;
  }
#pragma unroll
  for (int b = 0; b < 2; ++b) {
#pragma unroll
    for (int e = 0; e < 8; ++e) w[e] = f2bf(f2[b * 8 + e]);
    *(u16x8*)(dst + 32 + b * 8) = w;
  }
#pragma unroll
  for (int e = 0; e < 8; ++e) w[e] = 0;
  *(u16x8*)(dst + 48) = w;
  *(u16x8*)(dst + 56) = w;
}

// ---------------- kernel 3: tiny z-axis attention ----------------
__global__ __launch_bounds__(256) void k_attn(const float* __restrict__ pooled_sum,
    const float* __restrict__ ln_w, const float* __restrict__ ln_b,
    const float* __restrict__ wq, const float* __restrict__ bq,
    const float* __restrict__ wk, const float* __restrict__ bk,
    const float* __restrict__ wv, const float* __restrict__ bv,
    const float* __restrict__ wo, const float* __restrict__ bo,
    const float* __restrict__ relz, const float* __restrict__ attn_gamma,
    float* __restrict__ o_scaled) {
  __shared__ float pooled[2048];
  __shared__ float q[512], k[512], v[512], att[4096], tz[512];
  const int tid = threadIdx.x;
  for (int i = tid; i < 2048; i += 256) {
    int c = i & 63;
    pooled[i] = ln_w[c] * pooled_sum[i] * (1.0f / 16384.0f) + ln_b[c];
  }
  __syncthreads();
  for (int i = tid; i < 512; i += 256) {
    int z = i >> 4, e = i & 15;
    float aq = bq[e], ak = bk[e], av = bv[e];
    for (int c = 0; c < 64; ++c) {
      float p = pooled[z * 64 + c];
      aq += p * wq[c * 16 + e]; ak += p * wk[c * 16 + e]; av += p * wv[c * 16 + e];
    }
    q[i] = aq; k[i] = ak; v[i] = av;
  }
  __syncthreads();
  if (tid < 128) {
    int h = tid >> 5, zi = tid & 31;
    float s[32]; float mx = -1e30f;
#pragma unroll
    for (int j = 0; j < 32; ++j) {
      float d = 0.f;
#pragma unroll
      for (int e = 0; e < 4; ++e) d += q[zi * 16 + h * 4 + e] * k[j * 16 + h * 4 + e];
      d = d * 0.5f + relz[h * 65 + (j - zi + 32)];
      s[j] = d; mx = fmaxf(mx, d);
    }
    float ssum = 0.f;
#pragma unroll
    for (int j = 0; j < 32; ++j) { s[j] = __expf(s[j] - mx); ssum += s[j]; }
    float inv = 1.0f / ssum;
#pragma unroll
    for (int j = 0; j < 32; ++j) att[(h * 32 + zi) * 32 + j] = s[j] * inv;
  }
  __syncthreads();
  for (int i = tid; i < 512; i += 256) {
    int z = i >> 4, hd = i & 15, h = hd >> 2;
    float a = 0.f;
    for (int j = 0; j < 32; ++j) a += att[(h * 32 + z) * 32 + j] * v[j * 16 + hd];
    tz[i] = a;
  }
  __syncthreads();
  const float gamma = attn_gamma[0];
  for (int i = tid; i < 2048; i += 256) {
    int z = i >> 6, c = i & 63;
    float a = bo[c];
    for (int hd = 0; hd < 16; ++hd) a += tz[z * 16 + hd] * wo[hd * 64 + c];
    o_scaled[i] = gamma * a;
  }
}

// ---------------- kernel 4: fuse_w [K][N] fp32 -> W_bf [kc][n][64] bf16 (transpose) ----------------
__global__ __launch_bounds__(256) void k_wconv(const float* __restrict__ fw,
                                               u16* __restrict__ W_bf) {
  const int ktile = blockIdx.x;  // 0..32
  const int ntile = blockIdx.y;  // 0..31
  __shared__ float tile[64][65];
  const int tid = threadIdx.x;
  {
    const int kk0 = tid >> 6, nn = tid & 63;
#pragma unroll
    for (int it = 0; it < 16; ++it) {
      int kk = it * 4 + kk0;
      int kg = ktile * 64 + kk;
      tile[kk][nn] = (kg < 2096) ? fw[(size_t)kg * NCH + ntile * 64 + nn] : 0.0f;
    }
  }
  __syncthreads();
  {
    const int kk = tid & 63, nn0 = tid >> 6;
#pragma unroll
    for (int it = 0; it < 16; ++it) {
      int n = it * 4 + nn0;
      W_bf[((size_t)ktile * NCH + ntile * 64 + n) * 64 + kk] = f2bf(tile[kk][n]);
    }
  }
}

// ---------------- kernel 5: main GEMM, 256x256 tile, 8-wave, 4-phase/K-tile counted-vmcnt ----------------
// BM=256 pix, BN=256 ch, BK=64. 8 waves = 4(wn, channel) x 2(wm, pixel). LDS 128 KB dbuf.
// Block remap: XCD x owns an 8-m-tile band x all 8 n-panels, so co-resident blocks on one
// XCD share BOTH A subtiles (8 blocks each) and W subtiles (4 blocks each) in its L2.
__global__ __launch_bounds__(512, 2) void k_gemm(
    const u16* __restrict__ A_bf, const u16* __restrict__ W_bf,
    const float* __restrict__ trans, const float* __restrict__ o_scaled,
    const float* __restrict__ fuse_b, const float* __restrict__ rdc_scale,
    float* __restrict__ out) {
  __shared__ __align__(16) u16 ls[65536];  // 128 KB
  const int tid = threadIdx.x;
  const int lane = tid & 63;
  const int wave = __builtin_amdgcn_readfirstlane(tid >> 6);
  const int bid = blockIdx.x;
  const int xcd = bid & 7, local = bid >> 3;
  const int mb = xcd * 8 + (local >> 3);   // m-band per XCD
  const int nb = local & 7;
  const int mbase = mb * 256, nbase = nb * 256;
  const int wm = wave & 1, wn = wave >> 1;

  const int srow = lane >> 3;
  const int sgoff = srow * 64 + (((lane & 7) ^ srow) << 3);  // pre-swizzled source offset
  const int r16 = lane & 15, kgrp = lane >> 4, x7 = lane & 7;

  u16* const lsb = ls;

#define LA(b, h) (lsb + (b) * 32768 + (h) * 8192)
#define LW(b, h) (lsb + (b) * 32768 + 16384 + (h) * 8192)
#define AHALF(t, h) (A_bf + ((size_t)(t) * HW_N + mbase + (h) * 128) * 64)
#define WHALF(t, h) (W_bf + ((size_t)(t) * NCH + nbase + (h) * 128) * 64)
#define STAGE(rows, ldsh)                                            \
  do {                                                               \
    gload_lds16((rows) + wave * 512 + sgoff, (ldsh) + wave * 512);   \
    gload_lds16((rows) + 4096 + wave * 512 + sgoff, (ldsh) + 4096 + wave * 512); \
  } while (0)
#define RD(base, row, s) \
  (*(const s16x8*)((const char*)(base) + (row) * 128 + (((((s) << 2) | kgrp) ^ x7) << 4)))

  f32x4 acc[4][8] = {};   // [f: 4 ch-frags][g: 8 pix-frags]

  // ---- prologue: tile0 (A+W) + tile1 A ----
  STAGE(AHALF(0, 0), LA(0, 0));
  STAGE(AHALF(0, 1), LA(0, 1));
  STAGE(WHALF(0, 0), LW(0, 0));
  STAGE(WHALF(0, 1), LW(0, 1));
  STAGE(AHALF(1, 0), LA(1, 0));
  STAGE(AHALF(1, 1), LA(1, 1));
  asm volatile("s_waitcnt vmcnt(4)" ::: "memory");
  __builtin_amdgcn_s_barrier();

  for (int t = 0; t < 33; ++t) {
    const int buf = t & 1, nbuf = buf ^ 1;
    const int tW = (t + 1 < 33) ? t + 1 : 32;   // clamp (keeps vmcnt counts uniform)
    const int tA = (t + 2 < 33) ? t + 2 : 32;
    const u16* la = LA(buf, wm);
    const u16* lw = LW(buf, wn >> 1);
    const int wrow = (wn & 1) * 64;
    s16x8 af[4][2], wf0[2][2], wf1[2][2];

    // ---- phase 1: ds A(qg0)+W(qf0); stage W(t+1); mfma f0..1 x g0..3 ----
#pragma unroll
    for (int g = 0; g < 4; ++g) {
      af[g][0] = RD(la, g * 16 + r16, 0);
      af[g][1] = RD(la, g * 16 + r16, 1);
    }
#pragma unroll
    for (int f = 0; f < 2; ++f) {
      wf0[f][0] = RD(lw, wrow + f * 16 + r16, 0);
      wf0[f][1] = RD(lw, wrow + f * 16 + r16, 1);
    }
    STAGE(WHALF(tW, 0), LW(nbuf, 0));
    STAGE(WHALF(tW, 1), LW(nbuf, 1));
    __builtin_amdgcn_s_barrier();
    asm volatile("s_waitcnt lgkmcnt(0)" ::: "memory");
    __builtin_amdgcn_sched_barrier(0);
    __builtin_amdgcn_s_setprio(1);
#pragma unroll
    for (int f = 0; f < 2; ++f)
#pragma unroll
      for (int g = 0; g < 4; ++g)
        acc[f][g] = __builtin_amdgcn_mfma_f32_16x16x32_bf16(wf0[f][0], af[g][0], acc[f][g], 0, 0, 0);
#pragma unroll
    for (int f = 0; f < 2; ++f)
#pragma unroll
      for (int g = 0; g < 4; ++g)
        acc[f][g] = __builtin_amdgcn_mfma_f32_16x16x32_bf16(wf0[f][1], af[g][1], acc[f][g], 0, 0, 0);
    __builtin_amdgcn_s_setprio(0);
    __builtin_amdgcn_s_barrier();

    // ---- phase 2: ds W(qf1); mfma f2..3 x g0..3 ----
#pragma unroll
    for (int f = 0; f < 2; ++f) {
      wf1[f][0] = RD(lw, wrow + (2 + f) * 16 + r16, 0);
      wf1[f][1] = RD(lw, wrow + (2 + f) * 16 + r16, 1);
    }
    __builtin_amdgcn_s_barrier();
    asm volatile("s_waitcnt lgkmcnt(0)" ::: "memory");
    __builtin_amdgcn_sched_barrier(0);
    __builtin_amdgcn_s_setprio(1);
#pragma unroll
    for (int f = 0; f < 2; ++f)
#pragma unroll
      for (int g = 0; g < 4; ++g)
        acc[2 + f][g] = __builtin_amdgcn_mfma_f32_16x16x32_bf16(wf1[f][0], af[g][0], acc[2 + f][g], 0, 0, 0);
#pragma unroll
    for (int f = 0; f < 2; ++f)
#pragma unroll
      for (int g = 0; g < 4; ++g)
        acc[2 + f][g] = __builtin_amdgcn_mfma_f32_16x16x32_bf16(wf1[f][1], af[g][1], acc[2 + f][g], 0, 0, 0);
    __builtin_amdgcn_s_setprio(0);
    __builtin_amdgcn_s_barrier();

    // ---- phase 3: ds A(qg1); mfma f2..3 x g4..7 ----
#pragma unroll
    for (int g = 0; g < 4; ++g) {
      af[g][0] = RD(la, 64 + g * 16 + r16, 0);
      af[g][1] = RD(la, 64 + g * 16 + r16, 1);
    }
    __builtin_amdgcn_s_barrier();
    asm volatile("s_waitcnt lgkmcnt(0)" ::: "memory");
    __builtin_amdgcn_sched_barrier(0);
    __builtin_amdgcn_s_setprio(1);
#pragma unroll
    for (int f = 0; f < 2; ++f)
#pragma unroll
      for (int g = 0; g < 4; ++g)
        acc[2 + f][4 + g] = __builtin_amdgcn_mfma_f32_16x16x32_bf16(wf1[f][0], af[g][0], acc[2 + f][4 + g], 0, 0, 0);
#pragma unroll
    for (int f = 0; f < 2; ++f)
#pragma unroll
      for (int g = 0; g < 4; ++g)
        acc[2 + f][4 + g] = __builtin_amdgcn_mfma_f32_16x16x32_bf16(wf1[f][1], af[g][1], acc[2 + f][4 + g], 0, 0, 0);
    __builtin_amdgcn_s_setprio(0);
    __builtin_amdgcn_s_barrier();

    // ---- phase 4: stage A(t+2); mfma f0..1 x g4..7 (reuse wf0); vmcnt(4) ----
    STAGE(AHALF(tA, 0), LA(buf, 0));
    STAGE(AHALF(tA, 1), LA(buf, 1));
    __builtin_amdgcn_s_setprio(1);
#pragma unroll
    for (int f = 0; f < 2; ++f)
#pragma unroll
      for (int g = 0; g < 4; ++g)
        acc[f][4 + g] = __builtin_amdgcn_mfma_f32_16x16x32_bf16(wf0[f][0], af[g][0], acc[f][4 + g], 0, 0, 0);
#pragma unroll
    for (int f = 0; f < 2; ++f)
#pragma unroll
      for (int g = 0; g < 4; ++g)
        acc[f][4 + g] = __builtin_amdgcn_mfma_f32_16x16x32_bf16(wf0[f][1], af[g][1], acc[f][4 + g], 0, 0, 0);
    __builtin_amdgcn_s_setprio(0);
    asm volatile("s_waitcnt vmcnt(4)" ::: "memory");
    __builtin_amdgcn_s_barrier();
  }

  asm volatile("s_waitcnt vmcnt(0)" ::: "memory");

  // epilogue: out[ch][pix] = trans + rdc*lrelu(acc + fuse_b) + o_scaled[ch]
  const float rdc = rdc_scale[0];
  const int rg = lane >> 4;
#pragma unroll
  for (int f = 0; f < 4; ++f) {
#pragma unroll
    for (int r = 0; r < 4; ++r) {
      const int row = nbase + wn * 64 + f * 16 + rg * 4 + r;  // channel
      const float ob = o_scaled[row], fb = fuse_b[row];
#pragma unroll
      for (int g = 0; g < 8; ++g) {
        const int col = mbase + wm * 128 + g * 16 + r16;       // pixel
        float v = lrelu(acc[f][g][r] + fb);
        const size_t idx = (size_t)row * HW_N + col;
        out[idx] = trans[idx] + rdc * v + ob;
      }
    }
  }
#undef LA
#undef LW
#undef AHALF
#undef WHALF
#undef STAGE
#undef RD
}

extern "C" void kernel_launch(void* const* d_in, const int* in_sizes, int n_in,
                              void* d_out, int out_size, void* d_ws, size_t ws_size,
                              hipStream_t stream) {
  (void)in_sizes; (void)n_in; (void)out_size; (void)ws_size;
  const float* trans = (const float*)d_in[0];
  const float* ln_w  = (const float*)d_in[1];
  const float* ln_b  = (const float*)d_in[2];
  const float* wq = (const float*)d_in[3];  const float* bq = (const float*)d_in[4];
  const float* wk = (const float*)d_in[5];  const float* bk = (const float*)d_in[6];
  const float* wv = (const float*)d_in[7];  const float* bv = (const float*)d_in[8];
  const float* wo = (const float*)d_in[9];  const float* bo = (const float*)d_in[10];
  const float* relz  = (const float*)d_in[11];
  const float* gamma = (const float*)d_in[12];
  const float* dw0 = (const float*)d_in[13]; const float* db0 = (const float*)d_in[14];
  const float* dw1 = (const float*)d_in[15]; const float* db1 = (const float*)d_in[16];
  const float* dw2 = (const float*)d_in[17]; const float* db2 = (const float*)d_in[18];
  const float* fuse_w = (const float*)d_in[19];
  const float* fuse_b = (const float*)d_in[20];
  const float* rdc    = (const float*)d_in[21];
  float* out = (float*)d_out;

  char* ws = (char*)d_ws;
  u16*   A_bf       = (u16*)ws;                      // 33*16384*64*2 = 69,206,016 B
  float* G_part     = (float*)(ws + 69206016);       // time-shared with W_bf
  u16*   Wd         = (u16*)(ws + 69206016 + 6291456);
  u16*   W_bf       = (u16*)(ws + 69206016);
  float* pooled_sum = (float*)(ws + 77856768);       // 8 KB
  float* o_scaled   = (float*)(ws + 77864960);       // 8 KB

  hipMemsetAsync(pooled_sum, 0, 2048 * sizeof(float), stream);
  k_stats<<<dim3(32, 64), 256, 0, stream>>>(trans, A_bf, pooled_sum);
  k_wdense<<<dim3(32), 256, 0, stream>>>(dw0, dw1, dw2, Wd);
  k_dgemm<<<dim3(128, 2), 256, 0, stream>>>(A_bf, Wd, G_part);
  k_dfin<<<dim3(64), 256, 0, stream>>>(G_part, dw1, dw2, db0, db1, db2, A_bf);
  k_attn<<<dim3(1), 256, 0, stream>>>(pooled_sum, ln_w, ln_b, wq, bq, wk, bk, wv, bv,
                                      wo, bo, relz, gamma, o_scaled);
  k_wconv<<<dim3(33, 32), 256, 0, stream>>>(fuse_w, W_bf);
  k_gemm<<<dim3(512), 512, 0, stream>>>(A_bf, W_bf, trans, o_scaled, fuse_b, rdc, out);
}

// Round 5
// 257.961 us; speedup vs baseline: 1.0385x; 1.0385x over previous
//
#include <hip/hip_runtime.h>

typedef unsigned short u16;
typedef short s16x8 __attribute__((ext_vector_type(8)));
typedef float f32x4 __attribute__((ext_vector_type(4)));
typedef u16 u16x8 __attribute__((ext_vector_type(8)));

#define HW_N 16384   // 128*128 pixels
#define NCH  2048
// A_bf layout: [kc 0..32][pixel 16384][64 k]  (slab 32 = dense features + pad)
// W_bf layout: [kc 0..32][ch 2048][64 k]
// Wd   layout: [kc 0..31][j 48][64 k]

__device__ __forceinline__ u16 f2bf(float f) {
  union { float f; unsigned u; } v; v.f = f;
  unsigned r = v.u + 0x7FFFu + ((v.u >> 16) & 1u);  // RNE
  return (u16)(r >> 16);
}
__device__ __forceinline__ float bf2f(u16 u) {
  union { unsigned u; float f; } v; v.u = ((unsigned)u) << 16; return v.f;
}
__device__ __forceinline__ float lrelu(float v) { return v >= 0.0f ? v : 0.2f * v; }

__device__ __forceinline__ void gload_lds16(const u16* g, u16* l) {
  __builtin_amdgcn_global_load_lds((const __attribute__((address_space(1))) void*)g,
                                   (__attribute__((address_space(3))) void*)l, 16, 0, 0);
}

// ---------------- kernel 1: LN stats + pooled partial + coalesced bf16 A copy ----------------
__global__ __launch_bounds__(256) void k_stats(const float* __restrict__ trans,
                                               u16* __restrict__ A_bf,
                                               float* __restrict__ pooled_sum) {
  const int z = blockIdx.x;
  const int tid = threadIdx.x;
  const int ptile = blockIdx.y;
  const int p = ptile * 256 + tid;
  const float* src = trans + (size_t)z * 64 * HW_N + p;
  float x[64];
#pragma unroll
  for (int c = 0; c < 64; ++c) x[c] = src[(size_t)c * HW_N];
  float sum = 0.f, sq = 0.f;
#pragma unroll
  for (int c = 0; c < 64; ++c) { sum += x[c]; sq += x[c] * x[c]; }
  const float mu = sum * (1.0f / 64.0f);
  const float var = sq * (1.0f / 64.0f) - mu * mu;
  const float rstd = rsqrtf(var + 1e-5f);

  __shared__ __align__(16) u16 rawt[256 * 64];
  __shared__ __align__(16) u16 normt[256 * 64];
  const int r7 = tid & 7;
#pragma unroll
  for (int c8 = 0; c8 < 8; ++c8) {
    u16x8 wr, wn;
#pragma unroll
    for (int e = 0; e < 8; ++e) {
      float xv = x[c8 * 8 + e];
      wr[e] = f2bf(xv);
      wn[e] = f2bf((xv - mu) * rstd);
    }
    const int off = tid * 64 + ((c8 ^ r7) << 3);
    *(u16x8*)&rawt[off] = wr;
    *(u16x8*)&normt[off] = wn;
  }
  __syncthreads();

  u16* gbase = A_bf + ((size_t)z * HW_N + (size_t)ptile * 256) * 64;
#pragma unroll
  for (int i = 0; i < 8; ++i) {
    const int o = i * 256 + tid;
    const int row = o >> 3, kc = o & 7;
    u16x8 v = *(const u16x8*)&rawt[row * 64 + ((kc ^ (row & 7)) << 3)];
    *(u16x8*)(gbase + o * 8) = v;
  }

  const int c = tid & 63, q = tid >> 6;
  const int kc2 = c >> 3, e2 = c & 7;
  float s = 0.f;
#pragma unroll 8
  for (int i = 0; i < 64; ++i) {
    const int row = q * 64 + i;
    s += bf2f(normt[row * 64 + ((kc2 ^ (row & 7)) << 3) + e2]);
  }
  __shared__ float red2[4][64];
  red2[q][c] = s;
  __syncthreads();
  if (tid < 64) {
    atomicAdd(&pooled_sum[z * 64 + tid],
              red2[0][tid] + red2[1][tid] + red2[2][tid] + red2[3][tid]);
  }
}

// ---------------- kernel 2a: pack dense weights (first 2048 rows) -> Wd bf16 ----------------
__global__ __launch_bounds__(256) void k_wdense(const float* __restrict__ dw0,
                                                const float* __restrict__ dw1,
                                                const float* __restrict__ dw2,
                                                u16* __restrict__ Wd) {
  const int kc = blockIdx.x;  // 0..31
  __shared__ float tile[64][49];
  for (int idx = threadIdx.x; idx < 3072; idx += 256) {
    const int kk = idx / 48, j = idx % 48;
    const int k = kc * 64 + kk;
    float v = (j < 16) ? dw0[k * 16 + j]
            : (j < 32) ? dw1[k * 16 + (j - 16)]
                       : dw2[k * 16 + (j - 32)];
    tile[kk][j] = v;
  }
  __syncthreads();
  for (int idx = threadIdx.x; idx < 3072; idx += 256) {
    const int j = idx / 64, kk = idx % 64;
    Wd[((size_t)kc * 48 + j) * 64 + kk] = f2bf(tile[kk][j]);
  }
}

// ---------------- kernel 2b: G[pix][48] = A_bf[:,0:2048] @ Wd  (MFMA, K-split 2) ----------------
__global__ __launch_bounds__(256) void k_dgemm(const u16* __restrict__ A_bf,
                                               const u16* __restrict__ Wd,
                                               float* __restrict__ G_part) {
  __shared__ __align__(16) u16 lsA[128 * 64];  // 16 KB
  __shared__ __align__(16) u16 lsW[48 * 64];   // 6 KB
  const int tid = threadIdx.x;
  const int lane = tid & 63;
  const int wave = __builtin_amdgcn_readfirstlane(tid >> 6);
  const int mb = blockIdx.x;
  const int ks = blockIdx.y;
  const int srow = lane >> 3;
  const int skg = (lane & 7) ^ srow;
  f32x4 acc[3][2] = {};

  for (int t = 0; t < 16; ++t) {
    const int kc = ks * 16 + t;
    const u16* slabA = A_bf + ((size_t)kc * HW_N + (size_t)mb * 128) * 64;
    const u16* slabW = Wd + (size_t)kc * 48 * 64;
#pragma unroll
    for (int i = 0; i < 4; ++i) {
      const int c = wave * 4 + i;
      gload_lds16(slabA + (c * 8 + srow) * 64 + skg * 8, &lsA[c * 512]);
    }
    if (wave < 3) {
#pragma unroll
      for (int i = 0; i < 2; ++i) {
        const int c = wave * 2 + i;
        gload_lds16(slabW + (c * 8 + srow) * 64 + skg * 8, &lsW[c * 512]);
      }
    }
    asm volatile("s_waitcnt vmcnt(0)" ::: "memory");
    __syncthreads();

    const int r16 = lane & 15, kgrp = lane >> 4, x7 = lane & 7;
#pragma unroll
    for (int s = 0; s < 2; ++s) {
      s16x8 wf[3], af[2];
#pragma unroll
      for (int f = 0; f < 3; ++f) {
        const int rowW = f * 16 + r16;
        wf[f] = *(const s16x8*)((const char*)lsW + rowW * 128 + (((s * 4 + kgrp) ^ x7) << 4));
      }
#pragma unroll
      for (int g = 0; g < 2; ++g) {
        const int rowA = wave * 32 + g * 16 + r16;
        af[g] = *(const s16x8*)((const char*)lsA + rowA * 128 + (((s * 4 + kgrp) ^ x7) << 4));
      }
#pragma unroll
      for (int f = 0; f < 3; ++f)
#pragma unroll
        for (int g = 0; g < 2; ++g)
          acc[f][g] = __builtin_amdgcn_mfma_f32_16x16x32_bf16(wf[f], af[g], acc[f][g], 0, 0, 0);
    }
    __syncthreads();
  }

  const int r16 = lane & 15, rg = lane >> 4;
  float* gp = G_part + (size_t)ks * 48 * HW_N;
#pragma unroll
  for (int f = 0; f < 3; ++f)
#pragma unroll
    for (int r = 0; r < 4; ++r) {
      const int j = f * 16 + rg * 4 + r;
#pragma unroll
      for (int g = 0; g < 2; ++g) {
        const int pix = mb * 128 + wave * 32 + g * 16 + r16;
        gp[(size_t)j * HW_N + pix] = acc[f][g][r];
      }
    }
}

// ---------------- kernel 2c: finalize dense chain -> A_bf slab 32 ----------------
__global__ __launch_bounds__(256) void k_dfin(const float* __restrict__ G_part,
    const float* __restrict__ dw1, const float* __restrict__ dw2,
    const float* __restrict__ db0, const float* __restrict__ db1,
    const float* __restrict__ db2, u16* __restrict__ A_bf) {
  const int tid = threadIdx.x;
  const int pix = blockIdx.x * 256 + tid;
  __shared__ float w1t[16][16];
  __shared__ float w2t[32][16];
  __shared__ float biases[48];
  if (tid < 256) w1t[tid >> 4][tid & 15] = dw1[(2048 + (tid >> 4)) * 16 + (tid & 15)];
  for (int idx = tid; idx < 512; idx += 256)
    w2t[idx >> 4][idx & 15] = dw2[(2048 + (idx >> 4)) * 16 + (idx & 15)];
  if (tid < 48) biases[tid] = (tid < 16) ? db0[tid] : (tid < 32) ? db1[tid - 16] : db2[tid - 32];
  __syncthreads();

  float g[48];
#pragma unroll
  for (int j = 0; j < 48; ++j)
    g[j] = G_part[(size_t)j * HW_N + pix] + G_part[(size_t)(48 + j) * HW_N + pix];

  float f0[16], f1[16], f2[16];
#pragma unroll
  for (int j = 0; j < 16; ++j) f0[j] = lrelu(g[j] + biases[j]);
#pragma unroll
  for (int j = 0; j < 16; ++j) {
    float a = g[16 + j] + biases[16 + j];
#pragma unroll
    for (int i = 0; i < 16; ++i) a += f0[i] * w1t[i][j];
    f1[j] = lrelu(a);
  }
#pragma unroll
  for (int j = 0; j < 16; ++j) {
    float a = g[32 + j] + biases[32 + j];
#pragma unroll
    for (int i = 0; i < 16; ++i) a += f0[i] * w2t[i][j];
#pragma unroll
    for (int i = 0; i < 16; ++i) a += f1[i] * w2t[16 + i][j];
    f2[j] = lrelu(a);
  }
  u16* dst = A_bf + ((size_t)32 * HW_N + pix) * 64;
  u16x8 w;
#pragma unroll
  for (int b = 0; b < 2; ++b) {
#pragma unroll
    for (int e = 0; e < 8; ++e) w[e] = f2bf(f0[b * 8 + e]);
    *(u16x8*)(dst + b * 8) = w;
  }
#pragma unroll
  for (int b = 0; b < 2; ++b) {
#pragma unroll
    for (int e = 0; e < 8; ++e) w[e] = f2bf(f1[b * 8 + e]);
    *(u16x8*)(dst + 16 + b * 8) = w;
  }
#pragma unroll
  for (int b = 0; b < 2; ++b) {
#pragma unroll
    for (int e = 0; e < 8; ++e) w[e] = f2bf(f2[b * 8 + e]);
    *(u16x8*)(dst + 32 + b * 8) = w;
  }
#pragma unroll
  for (int e = 0; e < 8; ++e) w[e] = 0;
  *(u16x8*)(dst + 48) = w;
  *(u16x8*)(dst + 56) = w;
}

// ---------------- kernel 3: tiny z-axis attention ----------------
__global__ __launch_bounds__(256) void k_attn(const float* __restrict__ pooled_sum,
    const float* __restrict__ ln_w, const float* __restrict__ ln_b,
    const float* __restrict__ wq, const float* __restrict__ bq,
    const float* __restrict__ wk, const float* __restrict__ bk,
    const float* __restrict__ wv, const float* __restrict__ bv,
    const float* __restrict__ wo, const float* __restrict__ bo,
    const float* __restrict__ relz, const float* __restrict__ attn_gamma,
    float* __restrict__ o_scaled) {
  __shared__ float pooled[2048];
  __shared__ float q[512], k[512], v[512], att[4096], tz[512];
  const int tid = threadIdx.x;
  for (int i = tid; i < 2048; i += 256) {
    int c = i & 63;
    pooled[i] = ln_w[c] * pooled_sum[i] * (1.0f / 16384.0f) + ln_b[c];
  }
  __syncthreads();
  for (int i = tid; i < 512; i += 256) {
    int z = i >> 4, e = i & 15;
    float aq = bq[e], ak = bk[e], av = bv[e];
    for (int c = 0; c < 64; ++c) {
      float p = pooled[z * 64 + c];
      aq += p * wq[c * 16 + e]; ak += p * wk[c * 16 + e]; av += p * wv[c * 16 + e];
    }
    q[i] = aq; k[i] = ak; v[i] = av;
  }
  __syncthreads();
  if (tid < 128) {
    int h = tid >> 5, zi = tid & 31;
    float s[32]; float mx = -1e30f;
#pragma unroll
    for (int j = 0; j < 32; ++j) {
      float d = 0.f;
#pragma unroll
      for (int e = 0; e < 4; ++e) d += q[zi * 16 + h * 4 + e] * k[j * 16 + h * 4 + e];
      d = d * 0.5f + relz[h * 65 + (j - zi + 32)];
      s[j] = d; mx = fmaxf(mx, d);
    }
    float ssum = 0.f;
#pragma unroll
    for (int j = 0; j < 32; ++j) { s[j] = __expf(s[j] - mx); ssum += s[j]; }
    float inv = 1.0f / ssum;
#pragma unroll
    for (int j = 0; j < 32; ++j) att[(h * 32 + zi) * 32 + j] = s[j] * inv;
  }
  __syncthreads();
  for (int i = tid; i < 512; i += 256) {
    int z = i >> 4, hd = i & 15, h = hd >> 2;
    float a = 0.f;
    for (int j = 0; j < 32; ++j) a += att[(h * 32 + z) * 32 + j] * v[j * 16 + hd];
    tz[i] = a;
  }
  __syncthreads();
  const float gamma = attn_gamma[0];
  for (int i = tid; i < 2048; i += 256) {
    int z = i >> 6, c = i & 63;
    float a = bo[c];
    for (int hd = 0; hd < 16; ++hd) a += tz[z * 16 + hd] * wo[hd * 64 + c];
    o_scaled[i] = gamma * a;
  }
}

// ---------------- kernel 4: fuse_w [K][N] fp32 -> W_bf [kc][n][64] bf16 (transpose) ----------------
__global__ __launch_bounds__(256) void k_wconv(const float* __restrict__ fw,
                                               u16* __restrict__ W_bf) {
  const int ktile = blockIdx.x;  // 0..32
  const int ntile = blockIdx.y;  // 0..31
  __shared__ float tile[64][65];
  const int tid = threadIdx.x;
  {
    const int kk0 = tid >> 6, nn = tid & 63;
#pragma unroll
    for (int it = 0; it < 16; ++it) {
      int kk = it * 4 + kk0;
      int kg = ktile * 64 + kk;
      tile[kk][nn] = (kg < 2096) ? fw[(size_t)kg * NCH + ntile * 64 + nn] : 0.0f;
    }
  }
  __syncthreads();
  {
    const int kk = tid & 63, nn0 = tid >> 6;
#pragma unroll
    for (int it = 0; it < 16; ++it) {
      int n = it * 4 + nn0;
      W_bf[((size_t)ktile * NCH + ntile * 64 + n) * 64 + kk] = f2bf(tile[kk][n]);
    }
  }
}

// ---------------- kernel 5: main GEMM, 256x256, 8-wave, software-pipelined quadrants ----------------
// Per K-tile: Q1(f01xg03) Q2(f23xg03) Q3(f23xg47) Q4(f01xg47). Each phase issues NEXT
// phase's ds_reads then MFMAs on regs read LAST phase (LDS service overlaps matrix pipe).
// ONE vmcnt(0)+s_barrier per K-tile (at Q4, before reading buf(t+1)); stages: W(t+1)@Q1,
// A(t+1)@Q2 (2-phase slack). Register dbuf of (wf0, afL) via named a/b sets.
__global__ __launch_bounds__(512, 2) void k_gemm(
    const u16* __restrict__ A_bf, const u16* __restrict__ W_bf,
    const float* __restrict__ trans, const float* __restrict__ o_scaled,
    const float* __restrict__ fuse_b, const float* __restrict__ rdc_scale,
    float* __restrict__ out) {
  __shared__ __align__(16) u16 ls[65536];  // 128 KB
  const int tid = threadIdx.x;
  const int lane = tid & 63;
  const int wave = __builtin_amdgcn_readfirstlane(tid >> 6);
  const int bid = blockIdx.x;
  const int nb = bid & 7;        // XCD owns one 256-ch W panel (L2-resident)
  const int mb = bid >> 3;
  const int mbase = mb * 256, nbase = nb * 256;
  const int wm = wave & 1;       // pixel half
  const int wn = wave >> 1;      // channel quarter
  const int wnh = wn >> 1;       // which 128-ch W half
  const int wrow = (wn & 1) * 64;

  const int srow = lane >> 3;
  const int sgoff = srow * 64 + (((lane & 7) ^ srow) << 3);
  const int r16 = lane & 15, kgrp = lane >> 4, x7 = lane & 7;

  u16* const lsb = ls;

#define LA(b, h) (lsb + (b) * 32768 + (h) * 8192)
#define LW(b, h) (lsb + (b) * 32768 + 16384 + (h) * 8192)
#define AHALF(t, h) (A_bf + ((size_t)(t) * HW_N + mbase + (h) * 128) * 64)
#define WHALF(t, h) (W_bf + ((size_t)(t) * NCH + nbase + (h) * 128) * 64)
#define STAGE(rows, ldsh)                                            \
  do {                                                               \
    gload_lds16((rows) + wave * 512 + sgoff, (ldsh) + wave * 512);   \
    gload_lds16((rows) + 4096 + wave * 512 + sgoff, (ldsh) + 4096 + wave * 512); \
  } while (0)
#define RD(base, row, s) \
  (*(const s16x8*)((const char*)(base) + (row) * 128 + (((((s) << 2) | kgrp) ^ x7) << 4)))
#define MF(a, b, c) __builtin_amdgcn_mfma_f32_16x16x32_bf16((a), (b), (c), 0, 0, 0)

  f32x4 acc[4][8] = {};          // [f: 4 ch-frags][g: 8 pix-frags]
  s16x8 wf0a[2][2], afLa[4][2];  // pipelined (wf0, afL) set A
  s16x8 wf0b[2][2], afLb[4][2];  // set B

  // ---- prologue: stage tile 0, read its (wf0, afL) ----
  STAGE(WHALF(0, 0), LW(0, 0));
  STAGE(WHALF(0, 1), LW(0, 1));
  STAGE(AHALF(0, 0), LA(0, 0));
  STAGE(AHALF(0, 1), LA(0, 1));
  asm volatile("s_waitcnt vmcnt(0)" ::: "memory");
  __builtin_amdgcn_s_barrier();
  {
    const u16* lw0 = LW(0, wnh);
    const u16* la0 = LA(0, wm);
#pragma unroll
    for (int f = 0; f < 2; ++f) {
      wf0a[f][0] = RD(lw0, wrow + f * 16 + r16, 0);
      wf0a[f][1] = RD(lw0, wrow + f * 16 + r16, 1);
    }
#pragma unroll
    for (int g = 0; g < 4; ++g) {
      afLa[g][0] = RD(la0, g * 16 + r16, 0);
      afLa[g][1] = RD(la0, g * 16 + r16, 1);
    }
  }

#define GBODY(T, W0C, ALC, W0N, ALN)                                           \
  {                                                                            \
    const int t = (T);                                                         \
    const int buf = t & 1, nbf = buf ^ 1;                                      \
    const int tn = (t + 1 < 33) ? t + 1 : 32;                                  \
    const u16* la = LA(buf, wm);                                               \
    const u16* lw = LW(buf, wnh);                                              \
    s16x8 wf1[2][2], afH[4][2];                                                \
    /* Q1: read wf1(t); stage W(t+1); MFMA f01 x g03 */                        \
    _Pragma("unroll") for (int f = 0; f < 2; ++f) {                            \
      wf1[f][0] = RD(lw, wrow + 32 + f * 16 + r16, 0);                         \
      wf1[f][1] = RD(lw, wrow + 32 + f * 16 + r16, 1);                         \
    }                                                                          \
    STAGE(WHALF(tn, 0), LW(nbf, 0));                                           \
    STAGE(WHALF(tn, 1), LW(nbf, 1));                                           \
    __builtin_amdgcn_s_setprio(1);                                             \
    _Pragma("unroll") for (int f = 0; f < 2; ++f)                              \
      _Pragma("unroll") for (int g = 0; g < 4; ++g) {                          \
        acc[f][g] = MF(W0C[f][0], ALC[g][0], acc[f][g]);                       \
        acc[f][g] = MF(W0C[f][1], ALC[g][1], acc[f][g]);                       \
      }                                                                        \
    __builtin_amdgcn_s_setprio(0);                                             \
    /* Q2: read afH(t); stage A(t+1); MFMA f23 x g03 */                        \
    _Pragma("unroll") for (int g = 0; g < 4; ++g) {                            \
      afH[g][0] = RD(la, 64 + g * 16 + r16, 0);                                \
      afH[g][1] = RD(la, 64 + g * 16 + r16, 1);                                \
    }                                                                          \
    STAGE(AHALF(tn, 0), LA(nbf, 0));                                           \
    STAGE(AHALF(tn, 1), LA(nbf, 1));                                           \
    __builtin_amdgcn_s_setprio(1);                                             \
    _Pragma("unroll") for (int f = 0; f < 2; ++f)                              \
      _Pragma("unroll") for (int g = 0; g < 4; ++g) {                          \
        acc[2 + f][g] = MF(wf1[f][0], ALC[g][0], acc[2 + f][g]);               \
        acc[2 + f][g] = MF(wf1[f][1], ALC[g][1], acc[2 + f][g]);               \
      }                                                                        \
    __builtin_amdgcn_s_setprio(0);                                             \
    /* Q3: MFMA f23 x g47 (no reads) */                                        \
    __builtin_amdgcn_s_setprio(1);                                             \
    _Pragma("unroll") for (int f = 0; f < 2; ++f)                              \
      _Pragma("unroll") for (int g = 0; g < 4; ++g) {                          \
        acc[2 + f][4 + g] = MF(wf1[f][0], afH[g][0], acc[2 + f][4 + g]);       \
        acc[2 + f][4 + g] = MF(wf1[f][1], afH[g][1], acc[2 + f][4 + g]);       \
      }                                                                        \
    __builtin_amdgcn_s_setprio(0);                                             \
    /* Q4: vmcnt drain of this tile's stages; barrier; read (wf0,afL)(t+1);    \
       MFMA f01 x g47 */                                                       \
    asm volatile("s_waitcnt vmcnt(0)" ::: "memory");                           \
    __builtin_amdgcn_s_barrier();                                              \
    {                                                                          \
      const u16* lan = LA(nbf, wm);                                            \
      const u16* lwn = LW(nbf, wnh);                                           \
      _Pragma("unroll") for (int f = 0; f < 2; ++f) {                          \
        W0N[f][0] = RD(lwn, wrow + f * 16 + r16, 0);                           \
        W0N[f][1] = RD(lwn, wrow + f * 16 + r16, 1);                           \
      }                                                                        \
      _Pragma("unroll") for (int g = 0; g < 4; ++g) {                          \
        ALN[g][0] = RD(lan, g * 16 + r16, 0);                                  \
        ALN[g][1] = RD(lan, g * 16 + r16, 1);                                  \
      }                                                                        \
    }                                                                          \
    __builtin_amdgcn_s_setprio(1);                                             \
    _Pragma("unroll") for (int f = 0; f < 2; ++f)                              \
      _Pragma("unroll") for (int g = 0; g < 4; ++g) {                          \
        acc[f][4 + g] = MF(W0C[f][0], afH[g][0], acc[f][4 + g]);               \
        acc[f][4 + g] = MF(W0C[f][1], afH[g][1], acc[f][4 + g]);               \
      }                                                                        \
    __builtin_amdgcn_s_setprio(0);                                             \
  }

  for (int u = 0; u < 16; ++u) {
    GBODY(2 * u, wf0a, afLa, wf0b, afLb);
    GBODY(2 * u + 1, wf0b, afLb, wf0a, afLa);
  }
  GBODY(32, wf0a, afLa, wf0b, afLb);

  asm volatile("s_waitcnt vmcnt(0)" ::: "memory");

  // epilogue: out[ch][pix] = trans + rdc*lrelu(acc + fuse_b) + o_scaled[ch]
  const float rdc = rdc_scale[0];
  const int rg = lane >> 4;
#pragma unroll
  for (int f = 0; f < 4; ++f) {
#pragma unroll
    for (int r = 0; r < 4; ++r) {
      const int row = nbase + wn * 64 + f * 16 + rg * 4 + r;  // channel
      const float ob = o_scaled[row], fb = fuse_b[row];
#pragma unroll
      for (int g = 0; g < 8; ++g) {
        const int col = mbase + wm * 128 + g * 16 + r16;       // pixel
        float v = lrelu(acc[f][g][r] + fb);
        const size_t idx = (size_t)row * HW_N + col;
        out[idx] = trans[idx] + rdc * v + ob;
      }
    }
  }
#undef GBODY
#undef LA
#undef LW
#undef AHALF
#undef WHALF
#undef STAGE
#undef RD
#undef MF
}

extern "C" void kernel_launch(void* const* d_in, const int* in_sizes, int n_in,
                              void* d_out, int out_size, void* d_ws, size_t ws_size,
                              hipStream_t stream) {
  (void)in_sizes; (void)n_in; (void)out_size; (void)ws_size;
  const float* trans = (const float*)d_in[0];
  const float* ln_w  = (const float*)d_in[1];
  const float* ln_b  = (const float*)d_in[2];
  const float* wq = (const float*)d_in[3];  const float* bq = (const float*)d_in[4];
  const float* wk = (const float*)d_in[5];  const float* bk = (const float*)d_in[6];
  const float* wv = (const float*)d_in[7];  const float* bv = (const float*)d_in[8];
  const float* wo = (const float*)d_in[9];  const float* bo = (const float*)d_in[10];
  const float* relz  = (const float*)d_in[11];
  const float* gamma = (const float*)d_in[12];
  const float* dw0 = (const float*)d_in[13]; const float* db0 = (const float*)d_in[14];
  const float* dw1 = (const float*)d_in[15]; const float* db1 = (const float*)d_in[16];
  const float* dw2 = (const float*)d_in[17]; const float* db2 = (const float*)d_in[18];
  const float* fuse_w = (const float*)d_in[19];
  const float* fuse_b = (const float*)d_in[20];
  const float* rdc    = (const float*)d_in[21];
  float* out = (float*)d_out;

  char* ws = (char*)d_ws;
  u16*   A_bf       = (u16*)ws;                      // 33*16384*64*2 = 69,206,016 B
  float* G_part     = (float*)(ws + 69206016);       // time-shared with W_bf
  u16*   Wd         = (u16*)(ws + 69206016 + 6291456);
  u16*   W_bf       = (u16*)(ws + 69206016);
  float* pooled_sum = (float*)(ws + 77856768);       // 8 KB
  float* o_scaled   = (float*)(ws + 77864960);       // 8 KB

  hipMemsetAsync(pooled_sum, 0, 2048 * sizeof(float), stream);
  k_stats<<<dim3(32, 64), 256, 0, stream>>>(trans, A_bf, pooled_sum);
  k_wdense<<<dim3(32), 256, 0, stream>>>(dw0, dw1, dw2, Wd);
  k_dgemm<<<dim3(128, 2), 256, 0, stream>>>(A_bf, Wd, G_part);
  k_dfin<<<dim3(64), 256, 0, stream>>>(G_part, dw1, dw2, db0, db1, db2, A_bf);
  k_attn<<<dim3(1), 256, 0, stream>>>(pooled_sum, ln_w, ln_b, wq, bq, wk, bk, wv, bv,
                                      wo, bo, relz, gamma, o_scaled);
  k_wconv<<<dim3(33, 32), 256, 0, stream>>>(fuse_w, W_bf);
  k_gemm<<<dim3(512), 512, 0, stream>>>(A_bf, W_bf, trans, o_scaled, fuse_b, rdc, out);
}